// Round 1
// baseline (1305.410 us; speedup 1.0000x reference)
//
#include <hip/hip_runtime.h>
#include <hip/hip_bf16.h>

// Shapes (fixed by the reference)
#define QN 64
#define SQ 32
#define CN 256
#define SC 256
#define HD 768
#define DD 128
#define QT 31   // SQ-1
#define CT 255  // SC-1
#define CTP 256 // padded j-stride for transposed c_col

// ---- bf16 pack/unpack helpers (RNE) ----
static __device__ __forceinline__ unsigned short f2bf(float x) {
  unsigned u = __float_as_uint(x);
  unsigned r = 0x7FFFu + ((u >> 16) & 1u);
  return (unsigned short)((u + r) >> 16);
}
static __device__ __forceinline__ unsigned pack2(float a, float b) {
  return (unsigned)f2bf(a) | ((unsigned)f2bf(b) << 16);
}
static __device__ __forceinline__ float bflo(unsigned u) { return __uint_as_float(u << 16); }
static __device__ __forceinline__ float bfhi(unsigned u) { return __uint_as_float(u & 0xFFFF0000u); }

// ---------------------------------------------------------------------------
// Pooled: l2norm(h[:,0] * mask[:,0]) for q (64 rows) and c (256 rows).
// One block per row.
// ---------------------------------------------------------------------------
__global__ __launch_bounds__(256) void pooled_kernel(
    const float* __restrict__ qh, const int* __restrict__ qm,
    const float* __restrict__ ch, const int* __restrict__ cm,
    float* __restrict__ outq, float* __restrict__ outc) {
  int bid = blockIdx.x;
  const float* src;
  float* dst;
  float m;
  if (bid < QN) {
    src = qh + (size_t)bid * SQ * HD;
    m = (float)qm[bid * SQ];
    dst = outq + (size_t)bid * HD;
  } else {
    int b = bid - QN;
    src = ch + (size_t)b * SC * HD;
    m = (float)cm[b * SC];
    dst = outc + (size_t)b * HD;
  }
  int tid = threadIdx.x;
  float ss = 0.f;
  for (int k = tid; k < HD; k += 256) {
    float v = src[k] * m;
    ss += v * v;
  }
  __shared__ float red[4];
  int lane = tid & 63, wv = tid >> 6;
  for (int off = 32; off; off >>= 1) ss += __shfl_xor(ss, off);
  if (lane == 0) red[wv] = ss;
  __syncthreads();
  float tot = red[0] + red[1] + red[2] + red[3];
  float inv = 1.f / fmaxf(sqrtf(tot), 1e-12f);
  for (int k = tid; k < HD; k += 256) dst[k] = src[k] * m * inv;
}

// ---------------------------------------------------------------------------
// Projection: col[b, t, :] = l2norm((h[b, t+1, :]*mask) @ W + bias)
// Block: 128 threads (2 waves). Wave w handles tokens chunk*16 + w*8 .. +7.
// Thread lane owns output dims d = 2*lane, 2*lane+1 (within its wave).
// Output packed bf16 pairs:
//   transposed==0 (q): out[(b*T + tok)*64 + lane]        (row-major)
//   transposed==1 (c): out[(b*64 + lane)*CTP + tok]      (n-major, j-padded)
// ---------------------------------------------------------------------------
__global__ __launch_bounds__(128) void proj_kernel(
    const float* __restrict__ hidden, const int* __restrict__ mask,
    const float* __restrict__ W, const float* __restrict__ bias,
    unsigned* __restrict__ out, int S, int transposed) {
  int b = blockIdx.y;
  int t0 = blockIdx.x * 16;
  int T = S - 1;
  __shared__ float lds[16 * HD];  // 48 KB
  int tid = threadIdx.x, lane = tid & 63, wv = tid >> 6;

  // stage 16 masked token rows into LDS
  for (int r = 0; r < 16; ++r) {
    int tok = t0 + r;
    if (tok < T) {
      float m = (float)mask[b * S + tok + 1];
      const float* src = hidden + ((size_t)b * S + tok + 1) * HD;
      for (int k = tid; k < HD; k += 128) lds[r * HD + k] = src[k] * m;
    } else {
      for (int k = tid; k < HD; k += 128) lds[r * HD + k] = 0.f;
    }
  }
  __syncthreads();

  const float2* W2 = (const float2*)W;
  float2 bb = ((const float2*)bias)[lane];
  float acc0[8], acc1[8];
#pragma unroll
  for (int r = 0; r < 8; ++r) { acc0[r] = bb.x; acc1[r] = bb.y; }
  int rbase = wv * 8;

  for (int h0 = 0; h0 < HD; h0 += 4) {
    float2 w0 = W2[(h0 + 0) * 64 + lane];
    float2 w1 = W2[(h0 + 1) * 64 + lane];
    float2 w2 = W2[(h0 + 2) * 64 + lane];
    float2 w3 = W2[(h0 + 3) * 64 + lane];
#pragma unroll
    for (int r = 0; r < 8; ++r) {
      float4 qa = *(const float4*)&lds[(rbase + r) * HD + h0];
      float s0 = acc0[r], s1 = acc1[r];
      s0 = fmaf(qa.x, w0.x, s0); s1 = fmaf(qa.x, w0.y, s1);
      s0 = fmaf(qa.y, w1.x, s0); s1 = fmaf(qa.y, w1.y, s1);
      s0 = fmaf(qa.z, w2.x, s0); s1 = fmaf(qa.z, w2.y, s1);
      s0 = fmaf(qa.w, w3.x, s0); s1 = fmaf(qa.w, w3.y, s1);
      acc0[r] = s0; acc1[r] = s1;
    }
  }

  // per-token l2norm (full 128 dims live inside one wave) + packed store
#pragma unroll
  for (int r = 0; r < 8; ++r) {
    int tok = t0 + rbase + r;
    float ss = acc0[r] * acc0[r] + acc1[r] * acc1[r];
    for (int off = 32; off; off >>= 1) ss += __shfl_xor(ss, off);
    float inv = 1.f / fmaxf(sqrtf(ss), 1e-12f);
    if (tok < T) {
      unsigned p = pack2(acc0[r] * inv, acc1[r] * inv);
      if (!transposed)
        out[((size_t)b * T + tok) * 64 + lane] = p;
      else
        out[((size_t)b * 64 + lane) * CTP + tok] = p;
    }
  }
}

// ---------------------------------------------------------------------------
// Sim: sim[q,c] = (sum_i max_j dot(q_col[q,i], c_col[c,j])) / denom[q]
// Block per (q,c): 128 threads. q_col[q] (31x128 f32) in LDS.
// Thread tid accumulates 31 dots for j0=tid and j1=tid+128.
// ---------------------------------------------------------------------------
__global__ __launch_bounds__(128) void sim_kernel(
    const unsigned* __restrict__ qcol,   // [64][31][64] packed bf16x2
    const unsigned* __restrict__ ccolT,  // [256][64][256] packed bf16x2
    const int* __restrict__ qmask,
    float* __restrict__ sim) {
  int q = blockIdx.x, c = blockIdx.y;
  __shared__ float qs[QT * DD];  // 15872 B
  int tid = threadIdx.x;

  for (int idx = tid; idx < QT * 64; idx += 128) {
    unsigned u = qcol[(size_t)q * QT * 64 + idx];
    qs[2 * idx] = bflo(u);
    qs[2 * idx + 1] = bfhi(u);
  }
  __syncthreads();

  float d0[QT], d1[QT];
#pragma unroll
  for (int i = 0; i < QT; ++i) { d0[i] = 0.f; d1[i] = 0.f; }

  int j0 = tid;
  int j1 = tid + 128;
  int j1c = (j1 < CT) ? j1 : (CT - 1);
  const unsigned* cb = ccolT + (size_t)c * 64 * CTP;

  for (int n2 = 0; n2 < 64; n2 += 4) {  // 8 dims per iteration
    float c0[8], c1[8];
#pragma unroll
    for (int k = 0; k < 4; ++k) {
      unsigned u0 = cb[(n2 + k) * CTP + j0];
      unsigned u1 = cb[(n2 + k) * CTP + j1c];
      c0[2 * k] = bflo(u0); c0[2 * k + 1] = bfhi(u0);
      c1[2 * k] = bflo(u1); c1[2 * k + 1] = bfhi(u1);
    }
#pragma unroll
    for (int i = 0; i < QT; ++i) {
      const float* qp = &qs[i * DD + 2 * n2];
      float4 a = *(const float4*)qp;
      float4 bq = *(const float4*)(qp + 4);
      float s0 = d0[i], s1 = d1[i];
      s0 = fmaf(a.x, c0[0], s0);  s1 = fmaf(a.x, c1[0], s1);
      s0 = fmaf(a.y, c0[1], s0);  s1 = fmaf(a.y, c1[1], s1);
      s0 = fmaf(a.z, c0[2], s0);  s1 = fmaf(a.z, c1[2], s1);
      s0 = fmaf(a.w, c0[3], s0);  s1 = fmaf(a.w, c1[3], s1);
      s0 = fmaf(bq.x, c0[4], s0); s1 = fmaf(bq.x, c1[4], s1);
      s0 = fmaf(bq.y, c0[5], s0); s1 = fmaf(bq.y, c1[5], s1);
      s0 = fmaf(bq.z, c0[6], s0); s1 = fmaf(bq.z, c1[6], s1);
      s0 = fmaf(bq.w, c0[7], s0); s1 = fmaf(bq.w, c1[7], s1);
      d0[i] = s0; d1[i] = s1;
    }
  }

  if (j1 >= CT) {
#pragma unroll
    for (int i = 0; i < QT; ++i) d1[i] = -INFINITY;
  }

  __shared__ float mred[QT][2];
  int lane = tid & 63, wv = tid >> 6;
#pragma unroll
  for (int i = 0; i < QT; ++i) {
    float m = fmaxf(d0[i], d1[i]);
    for (int off = 32; off; off >>= 1) m = fmaxf(m, __shfl_xor(m, off));
    if (lane == 0) mred[i][wv] = m;
  }
  __syncthreads();
  if (tid == 0) {
    float tot = 0.f;
    for (int i = 0; i < QT; ++i) tot += fmaxf(mred[i][0], mred[i][1]);
    int dn = 0;
    for (int t = 1; t < SQ; ++t) dn += qmask[q * SQ + t];
    sim[q * CN + c] = tot / (float)dn;
  }
}

// ---------------------------------------------------------------------------
extern "C" void kernel_launch(void* const* d_in, const int* in_sizes, int n_in,
                              void* d_out, int out_size, void* d_ws, size_t ws_size,
                              hipStream_t stream) {
  const float* q_hidden = (const float*)d_in[0];
  const float* c_hidden = (const float*)d_in[1];
  const float* W = (const float*)d_in[2];
  const float* bias = (const float*)d_in[3];
  const int* q_mask = (const int*)d_in[4];
  const int* c_mask = (const int*)d_in[5];

  float* out = (float*)d_out;
  float* sim = out;                          // 64*256
  float* q_pooled = out + QN * CN;           // 64*768
  float* c_pooled = q_pooled + QN * HD;      // 256*768

  unsigned* qcol = (unsigned*)d_ws;                          // 64*31*64*4  = 507904 B
  unsigned* ccolT = (unsigned*)((char*)d_ws + (1u << 20));   // 256*64*256*4 = 16 MiB

  pooled_kernel<<<QN + CN, 256, 0, stream>>>(q_hidden, q_mask, c_hidden, c_mask,
                                             q_pooled, c_pooled);
  proj_kernel<<<dim3(2, QN), 128, 0, stream>>>(q_hidden, q_mask, W, bias, qcol, SQ, 0);
  proj_kernel<<<dim3(16, CN), 128, 0, stream>>>(c_hidden, c_mask, W, bias, ccolT, SC, 1);
  sim_kernel<<<dim3(QN, CN), 128, 0, stream>>>(qcol, ccolT, q_mask, sim);
}

// Round 2
// 381.628 us; speedup vs baseline: 3.4206x; 3.4206x over previous
//
#include <hip/hip_runtime.h>
#include <hip/hip_bf16.h>

// Shapes (fixed by the reference)
#define QN 64
#define SQ 32
#define CN 256
#define SC 256
#define HD 768
#define DD 128

typedef __attribute__((ext_vector_type(8))) short short8;   // 8 bf16 = 4 VGPR
typedef __attribute__((ext_vector_type(4))) float f32x4;    // MFMA acc

// ---- bf16 pack helpers (RNE) ----
static __device__ __forceinline__ unsigned short f2bf(float x) {
  unsigned u = __float_as_uint(x);
  unsigned r = 0x7FFFu + ((u >> 16) & 1u);
  return (unsigned short)((u + r) >> 16);
}
static __device__ __forceinline__ unsigned pack2(float a, float b) {
  return (unsigned)f2bf(a) | ((unsigned)f2bf(b) << 16);
}

// ---------------------------------------------------------------------------
// W^T convert: Wt[d][k] = bf16(W[k][d]).  128 blocks, tiny.
// ---------------------------------------------------------------------------
__global__ __launch_bounds__(256) void wcvt_kernel(const float* __restrict__ W,
                                                   unsigned short* __restrict__ Wt) {
  int d = blockIdx.x;
  for (int k = threadIdx.x; k < HD; k += 256)
    Wt[d * HD + k] = f2bf(W[(size_t)k * DD + d]);
}

// ---------------------------------------------------------------------------
// Pooled: l2norm(h[:,0] * mask[:,0]); q blocks also zero qcolP pad row 31.
// ---------------------------------------------------------------------------
__global__ __launch_bounds__(256) void pooled_kernel(
    const float* __restrict__ qh, const int* __restrict__ qm,
    const float* __restrict__ ch, const int* __restrict__ cm,
    float* __restrict__ outq, float* __restrict__ outc,
    unsigned short* __restrict__ qcolP) {
  int bid = blockIdx.x;
  const float* src;
  float* dst;
  float m;
  if (bid < QN) {
    src = qh + (size_t)bid * SQ * HD;
    m = (float)qm[bid * SQ];
    dst = outq + (size_t)bid * HD;
  } else {
    int b = bid - QN;
    src = ch + (size_t)b * SC * HD;
    m = (float)cm[b * SC];
    dst = outc + (size_t)b * HD;
  }
  int tid = threadIdx.x;
  float ss = 0.f;
  for (int k = tid; k < HD; k += 256) {
    float v = src[k] * m;
    ss += v * v;
  }
  __shared__ float red[4];
  int lane = tid & 63, wv = tid >> 6;
  for (int off = 32; off; off >>= 1) ss += __shfl_xor(ss, off);
  if (lane == 0) red[wv] = ss;
  __syncthreads();
  float tot = red[0] + red[1] + red[2] + red[3];
  float inv = 1.f / fmaxf(sqrtf(tot), 1e-12f);
  for (int k = tid; k < HD; k += 256) dst[k] = src[k] * m * inv;
  // zero the pad row (i = 31) of qcolP for this q
  if (bid < QN && tid < 64)
    ((unsigned*)(qcolP + ((size_t)bid * 32 + 31) * DD))[tid] = 0u;
}

// ---------------------------------------------------------------------------
// Projection GEMM (MFMA): col[g, :] = l2norm(bf16(h[g]*mask) @ Wt^T + bias)
// Tile: 64 tokens x 128 d, K=768 in BK=64 steps. 256 thr = 4 waves.
// Outputs row-major bf16 [token][128]:
//   flag==0 (q): qcolP[(b*32 + i)*128 + d], i = g%31        (row 31 pre-zeroed)
//   flag==1 (c): ccol [(b*256 + j)*128 + d], j = g%255; j==254 also dup to 255
// LDS tiles use a 16B-chunk XOR swizzle: phys_chunk = kc ^ (row & 7).
// ---------------------------------------------------------------------------
union ProjLDS {
  struct { unsigned short a[64 * 64]; unsigned short b[128 * 64]; } s;
  float c[64 * 132];
};

__global__ __launch_bounds__(256) void proj_kernel(
    const float* __restrict__ hidden, const int* __restrict__ mask,
    const unsigned short* __restrict__ Wt, const float* __restrict__ bias,
    unsigned short* __restrict__ out, int S, int flag) {
  __shared__ ProjLDS u;
  int tid = threadIdx.x, lane = tid & 63, w = tid >> 6;
  int lm = lane & 15, lq = lane >> 4;
  int T = S - 1;                       // 31 or 255
  int wm = w & 1, wn = w >> 1;

  // token/mask for the A-staging role (4 threads per row, 16 f32 each)
  int ar = tid >> 2, aseg = tid & 3;
  int ag = blockIdx.x * 64 + ar;
  int ab = ag / T, at = ag - ab * T;
  const float* hrow = hidden + ((size_t)ab * S + at + 1) * HD;
  float am = (float)mask[ab * S + at + 1];
  // B-staging role (2 threads per d row, 32 bf16 each)
  int bd = tid >> 1, bh = tid & 1;
  const unsigned short* wrow = Wt + (size_t)bd * HD + bh * 32;

  f32x4 acc[2][4];
#pragma unroll
  for (int i = 0; i < 2; ++i)
#pragma unroll
    for (int j = 0; j < 4; ++j) acc[i][j] = (f32x4){0.f, 0.f, 0.f, 0.f};

  for (int k0 = 0; k0 < HD; k0 += 64) {
    __syncthreads();
    // ---- stage A (64 tok x 64 k, f32 -> bf16, masked) ----
    {
      const float4* hp = (const float4*)(hrow + k0 + aseg * 16);
      float4 v0 = hp[0], v1 = hp[1], v2 = hp[2], v3 = hp[3];
      unsigned p[8];
      p[0] = pack2(v0.x * am, v0.y * am); p[1] = pack2(v0.z * am, v0.w * am);
      p[2] = pack2(v1.x * am, v1.y * am); p[3] = pack2(v1.z * am, v1.w * am);
      p[4] = pack2(v2.x * am, v2.y * am); p[5] = pack2(v2.z * am, v2.w * am);
      p[6] = pack2(v3.x * am, v3.y * am); p[7] = pack2(v3.z * am, v3.w * am);
      int kc0 = aseg * 2;
      int pk0 = kc0 ^ (ar & 7), pk1 = (kc0 + 1) ^ (ar & 7);
      *(uint4*)&u.s.a[(ar * 8 + pk0) * 8] = *(uint4*)&p[0];
      *(uint4*)&u.s.a[(ar * 8 + pk1) * 8] = *(uint4*)&p[4];
    }
    // ---- stage B (128 d x 64 k, already bf16) ----
    {
      const uint4* wp = (const uint4*)(wrow + k0);
#pragma unroll
      for (int j = 0; j < 4; ++j) {
        int kc = bh * 4 + j;
        int pk = kc ^ (bd & 7);
        *(uint4*)&u.s.b[(bd * 8 + pk) * 8] = wp[j];
      }
    }
    __syncthreads();
    // ---- MFMA: wave tile 32 tok x 64 d ----
#pragma unroll
    for (int kf = 0; kf < 2; ++kf) {
      short8 a2[2], b4[4];
#pragma unroll
      for (int mt = 0; mt < 2; ++mt) {
        int row = (wm * 2 + mt) * 16 + lm;
        int kc = kf * 4 + lq;
        a2[mt] = *(const short8*)&u.s.a[(row * 8 + (kc ^ (row & 7))) * 8];
      }
#pragma unroll
      for (int nt = 0; nt < 4; ++nt) {
        int row = (wn * 4 + nt) * 16 + lm;
        int kc = kf * 4 + lq;
        b4[nt] = *(const short8*)&u.s.b[(row * 8 + (kc ^ (row & 7))) * 8];
      }
#pragma unroll
      for (int mt = 0; mt < 2; ++mt)
#pragma unroll
        for (int nt = 0; nt < 4; ++nt)
          acc[mt][nt] = __builtin_amdgcn_mfma_f32_16x16x32_bf16(a2[mt], b4[nt], acc[mt][nt], 0, 0, 0);
    }
  }

  // ---- epilogue: C tile -> LDS, bias + l2norm, bf16 store ----
  __syncthreads();
#pragma unroll
  for (int mt = 0; mt < 2; ++mt)
#pragma unroll
    for (int nt = 0; nt < 4; ++nt)
#pragma unroll
      for (int r = 0; r < 4; ++r) {
        int row = (wm * 2 + mt) * 16 + lq * 4 + r;
        int col = (wn * 4 + nt) * 16 + lm;
        u.c[row * 132 + col] = acc[mt][nt][r];
      }
  __syncthreads();

  int r2 = tid >> 2, seg2 = tid & 3;
  float v[32];
  float ss = 0.f;
#pragma unroll
  for (int j = 0; j < 8; ++j) {
    float4 cv = *(const float4*)&u.c[r2 * 132 + seg2 * 32 + j * 4];
    float4 bv = *(const float4*)&bias[seg2 * 32 + j * 4];
    v[4 * j + 0] = cv.x + bv.x; v[4 * j + 1] = cv.y + bv.y;
    v[4 * j + 2] = cv.z + bv.z; v[4 * j + 3] = cv.w + bv.w;
#pragma unroll
    for (int e = 0; e < 4; ++e) ss += v[4 * j + e] * v[4 * j + e];
  }
  ss += __shfl_xor(ss, 1);
  ss += __shfl_xor(ss, 2);
  float inv = 1.f / fmaxf(sqrtf(ss), 1e-12f);

  unsigned pk[16];
#pragma unroll
  for (int j = 0; j < 16; ++j) pk[j] = pack2(v[2 * j] * inv, v[2 * j + 1] * inv);

  int g = blockIdx.x * 64 + r2;
  int b = g / T, tt = g - b * T;
  unsigned short* dst;
  if (!flag)
    dst = out + ((size_t)b * 32 + tt) * DD + seg2 * 32;
  else
    dst = out + ((size_t)b * 256 + tt) * DD + seg2 * 32;
  uint4* d4 = (uint4*)dst;
  d4[0] = *(uint4*)&pk[0];  d4[1] = *(uint4*)&pk[4];
  d4[2] = *(uint4*)&pk[8];  d4[3] = *(uint4*)&pk[12];
  if (flag && tt == 254) {   // duplicate token 254 into pad row 255
    uint4* d5 = (uint4*)(dst + DD);
    d5[0] = *(uint4*)&pk[0];  d5[1] = *(uint4*)&pk[4];
    d5[2] = *(uint4*)&pk[8];  d5[3] = *(uint4*)&pk[12];
  }
}

// ---------------------------------------------------------------------------
// Sim (MFMA): sim[q,c] = (sum_i max_j qcol[q,i]·ccol[c,j]) / denom[q]
// Block: 256 thr = 4 waves; 8 q per block (2 q per wave), 4 c looped.
// c tile (256 x 128 bf16 = 64 KB) staged in LDS with XOR-swizzled 16B chunks.
// A-frags in VGPRs; max deferred per j-tile (elementwise fmax on acc regs).
// ---------------------------------------------------------------------------
__global__ __launch_bounds__(256, 2) void sim_kernel(
    const unsigned short* __restrict__ qcolP,  // [64][32][128], row 31 zero
    const unsigned short* __restrict__ ccol,   // [256][256][128], row 255 dup
    const int* __restrict__ qmask,
    float* __restrict__ sim) {
  __shared__ unsigned short cbuf[256 * 128];   // exactly 64 KB
  int tid = threadIdx.x, lane = tid & 63, w = tid >> 6;
  int lm = lane & 15, lq = lane >> 4;
  int q0 = blockIdx.y * 8 + w * 2;
  int c0 = blockIdx.x * 4;

  // A fragments for this wave's 2 q's: [q2][i-tile][k-frag]
  short8 af[2][2][4];
#pragma unroll
  for (int q2 = 0; q2 < 2; ++q2)
#pragma unroll
    for (int it = 0; it < 2; ++it)
#pragma unroll
      for (int kf = 0; kf < 4; ++kf)
        af[q2][it][kf] = *(const short8*)(qcolP +
            (((size_t)(q0 + q2) * 32 + it * 16 + lm) * DD + kf * 32 + lq * 8));

  float dinv[2];
#pragma unroll
  for (int q2 = 0; q2 < 2; ++q2) {
    float v = (lane >= 1 && lane < 32) ? (float)qmask[(q0 + q2) * SQ + lane] : 0.f;
    for (int off = 1; off < 64; off <<= 1) v += __shfl_xor(v, off);
    dinv[q2] = 1.f / v;
  }

  for (int cc = 0; cc < 4; ++cc) {
    int c = c0 + cc;
    __syncthreads();
    const uint4* src = (const uint4*)(ccol + (size_t)c * SC * DD);
#pragma unroll
    for (int half = 0; half < 2; ++half) {
      uint4 tmp[8];
#pragma unroll
      for (int it = 0; it < 8; ++it) tmp[it] = src[(half * 8 + it) * 256 + tid];
#pragma unroll
      for (int it = 0; it < 8; ++it) {
        int idx = (half * 8 + it) * 256 + tid;
        int row = idx >> 4, kc = idx & 15;
        int pkc = (kc & 8) | ((kc & 7) ^ (row & 7));
        *(uint4*)&cbuf[(row * 16 + pkc) * 8] = tmp[it];
      }
    }
    __syncthreads();

    float cmx[2][2][4];
#pragma unroll
    for (int q2 = 0; q2 < 2; ++q2)
#pragma unroll
      for (int it = 0; it < 2; ++it)
#pragma unroll
        for (int r = 0; r < 4; ++r) cmx[q2][it][r] = -__builtin_inff();

    for (int jt = 0; jt < 16; ++jt) {
      short8 bf[4];
#pragma unroll
      for (int kf = 0; kf < 4; ++kf) {
        int row = jt * 16 + lm;
        int kc = kf * 4 + lq;
        int pkc = (kc & 8) | ((kc & 7) ^ (row & 7));
        bf[kf] = *(const short8*)&cbuf[(row * 16 + pkc) * 8];
      }
#pragma unroll
      for (int q2 = 0; q2 < 2; ++q2)
#pragma unroll
        for (int it = 0; it < 2; ++it) {
          f32x4 acc = (f32x4){0.f, 0.f, 0.f, 0.f};
#pragma unroll
          for (int kf = 0; kf < 4; ++kf)
            acc = __builtin_amdgcn_mfma_f32_16x16x32_bf16(af[q2][it][kf], bf[kf], acc, 0, 0, 0);
#pragma unroll
          for (int r = 0; r < 4; ++r) cmx[q2][it][r] = fmaxf(cmx[q2][it][r], acc[r]);
        }
    }

#pragma unroll
    for (int q2 = 0; q2 < 2; ++q2) {
#pragma unroll
      for (int off = 1; off < 16; off <<= 1)
#pragma unroll
        for (int it = 0; it < 2; ++it)
#pragma unroll
          for (int r = 0; r < 4; ++r)
            cmx[q2][it][r] = fmaxf(cmx[q2][it][r], __shfl_xor(cmx[q2][it][r], off));
      // rows of this quad: it*16 + lq*4 + r; pad row 31 = (it1, lq3, r3)
      float s = cmx[q2][0][0] + cmx[q2][0][1] + cmx[q2][0][2] + cmx[q2][0][3]
              + cmx[q2][1][0] + cmx[q2][1][1] + cmx[q2][1][2]
              + ((lq == 3) ? 0.f : cmx[q2][1][3]);
      s += __shfl_xor(s, 16);
      s += __shfl_xor(s, 32);
      if (lane == 0) sim[(q0 + q2) * CN + c] = s * dinv[q2];
    }
  }
}

// ---------------------------------------------------------------------------
extern "C" void kernel_launch(void* const* d_in, const int* in_sizes, int n_in,
                              void* d_out, int out_size, void* d_ws, size_t ws_size,
                              hipStream_t stream) {
  const float* q_hidden = (const float*)d_in[0];
  const float* c_hidden = (const float*)d_in[1];
  const float* W = (const float*)d_in[2];
  const float* bias = (const float*)d_in[3];
  const int* q_mask = (const int*)d_in[4];
  const int* c_mask = (const int*)d_in[5];

  float* out = (float*)d_out;
  float* sim = out;                      // 64*256
  float* q_pooled = out + QN * CN;       // 64*768
  float* c_pooled = q_pooled + QN * HD;  // 256*768

  unsigned short* Wt    = (unsigned short*)d_ws;                        // 128*768*2 = 192 KB
  unsigned short* qcolP = (unsigned short*)((char*)d_ws + (256 << 10)); // 64*32*128*2 = 512 KB
  unsigned short* ccol  = (unsigned short*)((char*)d_ws + (1 << 20));   // 256*256*128*2 = 16 MB

  wcvt_kernel<<<DD, 256, 0, stream>>>(W, Wt);
  pooled_kernel<<<QN + CN, 256, 0, stream>>>(q_hidden, q_mask, c_hidden, c_mask,
                                             q_pooled, c_pooled, qcolP);
  proj_kernel<<<31, 256, 0, stream>>>(q_hidden, q_mask, Wt, bias, qcolP, SQ, 0);
  proj_kernel<<<1020, 256, 0, stream>>>(c_hidden, c_mask, Wt, bias, ccol, SC, 1);
  sim_kernel<<<dim3(64, 8), 256, 0, stream>>>(qcolP, ccol, q_mask, sim);
}